// Round 7
// baseline (2932.185 us; speedup 1.0000x reference)
//
#include <hip/hip_runtime.h>
#include <math.h>

#define BB  32
#define SQl 200
#define SKV 200
#define DD  1024
#define NH  16
#define HDm 64
#define NL  6
#define FFD 2048

typedef __attribute__((ext_vector_type(8))) short  short8v;
typedef __attribute__((ext_vector_type(4))) float  floatx4;

#define SBAR()   __builtin_amdgcn_s_barrier()
#define VMCNT6() asm volatile("s_waitcnt vmcnt(6)" ::: "memory")
#define VMCNT0() asm volatile("s_waitcnt vmcnt(0)" ::: "memory")

// float -> bf16 bits, round-to-nearest-even
__device__ __forceinline__ ushort f2bf(float x) {
  uint u = __builtin_bit_cast(uint, x);
  u = (u + 0x7FFFu + ((u >> 16) & 1u)) >> 16;
  return (ushort)u;
}

__device__ __forceinline__ void gll16(const void* g, void* l) {
  __builtin_amdgcn_global_load_lds((const __attribute__((address_space(1))) void*)g,
                                   (__attribute__((address_space(3))) void*)l,
                                   16, 0, 0);
}

// ---------------- embedding + sinusoidal positional encoding ----------------
__global__ __launch_bounds__(256) void embed_pe_kernel(const int* __restrict__ qids,
                                                       const float* __restrict__ emb,
                                                       float* __restrict__ x) {
  int idx = blockIdx.x * 256 + threadIdx.x;
  int d   = idx & (DD - 1);
  int row = idx >> 10;
  int s   = row % SQl;
  int tok = qids[row];
  float expo = (float)(d & ~1) * (1.0f / (float)DD);
  float dv   = powf(10000.0f, expo);
  float ang  = (float)s / dv;
  float pe   = (d & 1) ? cosf(ang) : sinf(ang);
  x[idx] = emb[(size_t)tok * DD + d] + pe;
}

// ---------------- f32 -> bf16 elementwise ----------------
__global__ __launch_bounds__(256) void cvt_bf16_kernel(const float* __restrict__ in,
                                                       ushort* __restrict__ out, int n8) {
  int idx = blockIdx.x * 256 + threadIdx.x;
  if (idx >= n8) return;
  const floatx4 va = ((const floatx4*)in)[idx * 2];
  const floatx4 vb = ((const floatx4*)in)[idx * 2 + 1];
  short8v o;
  o[0] = (short)f2bf(va.x); o[1] = (short)f2bf(va.y);
  o[2] = (short)f2bf(va.z); o[3] = (short)f2bf(va.w);
  o[4] = (short)f2bf(vb.x); o[5] = (short)f2bf(vb.y);
  o[6] = (short)f2bf(vb.z); o[7] = (short)f2bf(vb.w);
  ((short8v*)out)[idx] = o;
}

// ---------------- batched transposes: W[K][N] f32 -> WT[N][K] bf16 ----------------
struct P8 { const float* p[8]; };
__global__ __launch_bounds__(256) void transpose48_kernel(P8 srcs, ushort* __restrict__ dst) {
  __shared__ float t[32][33];
  const size_t MEL = (size_t)DD * DD;
  const int z = blockIdx.z;
  const int arr = z / 6, l = z - arr * 6;
  const size_t base[8] = {0, MEL, 2*MEL, 18*MEL, 24*MEL, 30*MEL, 36*MEL, 42*MEL};
  const size_t lstr[8] = {3*MEL, 3*MEL, 3*MEL, MEL, MEL, MEL, MEL, MEL};
  const float* __restrict__ W = srcs.p[arr] + (size_t)l * MEL;
  ushort* __restrict__ WT = dst + base[arr] + (size_t)l * lstr[arr];
  const int n0 = blockIdx.x * 32, k0 = blockIdx.y * 32;
  const int tx = threadIdx.x & 31, ty = threadIdx.x >> 5;
#pragma unroll
  for (int i = 0; i < 4; ++i)
    t[ty + i * 8][tx] = W[(size_t)(k0 + ty + i * 8) * DD + n0 + tx];
  __syncthreads();
#pragma unroll
  for (int i = 0; i < 4; ++i)
    WT[(size_t)(n0 + ty + i * 8) * DD + k0 + tx] = f2bf(t[tx][ty + i * 8]);
}

__global__ __launch_bounds__(256) void transposeW_kernel(const float* __restrict__ src,
                                                         ushort* __restrict__ dst,
                                                         int K, int N) {
  __shared__ float t[32][33];
  const int z = blockIdx.z;
  const float* __restrict__ W = src + (size_t)z * K * N;
  ushort* __restrict__ WT = dst + (size_t)z * K * N;
  const int n0 = blockIdx.x * 32, k0 = blockIdx.y * 32;
  const int tx = threadIdx.x & 31, ty = threadIdx.x >> 5;
#pragma unroll
  for (int i = 0; i < 4; ++i)
    t[ty + i * 8][tx] = W[(size_t)(k0 + ty + i * 8) * N + n0 + tx];
  __syncthreads();
#pragma unroll
  for (int i = 0; i < 4; ++i)
    WT[(size_t)(n0 + ty + i * 8) * K + k0 + tx] = f2bf(t[tx][ty + i * 8]);
}

// ---------------- LayerNorm: wave per row, shfl-only reduction ----------------
template <int OBF16>
__global__ __launch_bounds__(256) void ln4_kernel(const float* __restrict__ in,
                                                  const float* __restrict__ gam,
                                                  const float* __restrict__ bet,
                                                  float* __restrict__ outf,
                                                  ushort* __restrict__ outb) {
  const int wid  = threadIdx.x >> 6;
  const int lane = threadIdx.x & 63;
  const int row  = blockIdx.x * 4 + wid;
  const float* ip = in + (size_t)row * DD;

  float4 x[4];
  float s = 0.f, sq = 0.f;
#pragma unroll
  for (int i = 0; i < 4; ++i) {
    x[i] = *(const float4*)&ip[i * 256 + lane * 4];
    s  += x[i].x + x[i].y + x[i].z + x[i].w;
    sq += x[i].x * x[i].x + x[i].y * x[i].y + x[i].z * x[i].z + x[i].w * x[i].w;
  }
#pragma unroll
  for (int msk = 1; msk < 64; msk <<= 1) {
    s  += __shfl_xor(s,  msk, 64);
    sq += __shfl_xor(sq, msk, 64);
  }
  const float m   = s * (1.0f / (float)DD);
  const float var = sq * (1.0f / (float)DD) - m * m;
  const float inv = rsqrtf(var + 1e-9f);

#pragma unroll
  for (int i = 0; i < 4; ++i) {
    const int c = i * 256 + lane * 4;
    const float4 g4 = *(const float4*)&gam[c];
    const float4 b4 = *(const float4*)&bet[c];
    float o0 = (x[i].x - m) * inv * g4.x + b4.x;
    float o1 = (x[i].y - m) * inv * g4.y + b4.y;
    float o2 = (x[i].z - m) * inv * g4.z + b4.z;
    float o3 = (x[i].w - m) * inv * g4.w + b4.w;
    if (OBF16) {
      uint2 pk;
      pk.x = (uint)f2bf(o0) | ((uint)f2bf(o1) << 16);
      pk.y = (uint)f2bf(o2) | ((uint)f2bf(o3) << 16);
      *(uint2*)&outb[(size_t)row * DD + c] = pk;
    } else {
      float4 ov; ov.x = o0; ov.y = o1; ov.z = o2; ov.w = o3;
      *(float4*)&outf[(size_t)row * DD + c] = ov;
    }
  }
}

struct BiasP { const float* p[6]; };   // bias.p[col>>10][col&1023]

// ---------------- gemm256: 256x256 tile, 8 waves, wave tile 128x64, BK=64 ----------
// Double-buffered 128 KB LDS; per K-tile: {issue 8 global_load_lds for t+1 ->
// 24 swizzled ds_read_b128 -> 64 MFMA (setprio) -> vmcnt(0) -> s_barrier}.
// LDS layout: [256 rows][8 slots of 16B]; physical slot p of row holds k-group
// p^(row&7) (conflict-free; staged via pre-swizzled global source).
template <int RELU, int ACC, int OBF16>
__global__ __launch_bounds__(512, 2) void gemm256_mfma(const ushort* __restrict__ A,
                                                       const ushort* __restrict__ BT,
                                                       BiasP bias,
                                                       float* __restrict__ C,
                                                       ushort* __restrict__ Cb,
                                                       int M, int N, int K, int ldc) {
  __shared__ short8v As[2 * 2048];   // 64 KB
  __shared__ short8v Bs[2 * 2048];   // 64 KB
  const int tid  = threadIdx.x;
  const int w    = tid >> 6;          // 0..7
  const int lane = tid & 63;
  const int bm = blockIdx.y * 256;
  const int bn = blockIdx.x * 256;
  const int wm = (w >> 2) * 128;      // 2 M-waves
  const int wn = (w & 3) * 64;        // 4 N-waves
  const int lq = lane & 15;
  const int lg = lane >> 4;

  // staging: thread covers slots {i*512 + tid}, i=0..3, per operand
  const ushort* aS[4];
  const ushort* bS[4];
#pragma unroll
  for (int i = 0; i < 4; ++i) {
    const int s   = i * 512 + tid;
    const int row = s >> 3;
    const int kg  = (s & 7) ^ (row & 7);
    aS[i] = A  + (size_t)(bm + row) * K + kg * 8;
    bS[i] = BT + (size_t)(bn + row) * K + kg * 8;
  }

  // fragment read indices for ksub0; ksub1 = idx^4
  int aIdx[8], bIdx[4];
#pragma unroll
  for (int i = 0; i < 8; ++i) {
    const int mr = wm + i * 16 + lq;
    aIdx[i] = mr * 8 + (lg ^ (mr & 7));
  }
#pragma unroll
  for (int i = 0; i < 4; ++i) {
    const int nr = wn + i * 16 + lq;
    bIdx[i] = nr * 8 + (lg ^ (nr & 7));
  }

  floatx4 acc[8][4];
  const floatx4 fz = {0.f, 0.f, 0.f, 0.f};
#pragma unroll
  for (int mi = 0; mi < 8; ++mi)
#pragma unroll
    for (int ni = 0; ni < 4; ++ni) acc[mi][ni] = fz;

  const int nt = K >> 6;

  // prologue: stage tile 0 into buffer 0
#pragma unroll
  for (int i = 0; i < 4; ++i) gll16(aS[i], &As[i * 512 + w * 64]);
#pragma unroll
  for (int i = 0; i < 4; ++i) gll16(bS[i], &Bs[i * 512 + w * 64]);
  VMCNT0();
  SBAR();

  int cur = 0;
  for (int t = 0; t < nt; ++t) {
    if (t + 1 < nt) {                  // stage-early: t+1 into the other buffer
      const int ko = (t + 1) * 64;
      const int db = (cur ^ 1) * 2048;
#pragma unroll
      for (int i = 0; i < 4; ++i) gll16(aS[i] + ko, &As[db + i * 512 + w * 64]);
#pragma unroll
      for (int i = 0; i < 4; ++i) gll16(bS[i] + ko, &Bs[db + i * 512 + w * 64]);
    }
    const int cb = cur * 2048;
#pragma unroll
    for (int kk = 0; kk < 2; ++kk) {
      short8v af[8], bf_[4];
#pragma unroll
      for (int i = 0; i < 8; ++i) af[i]  = As[cb + (aIdx[i] ^ (kk * 4))];
#pragma unroll
      for (int i = 0; i < 4; ++i) bf_[i] = Bs[cb + (bIdx[i] ^ (kk * 4))];
      __builtin_amdgcn_s_setprio(1);
#pragma unroll
      for (int mi = 0; mi < 8; ++mi)
#pragma unroll
        for (int ni = 0; ni < 4; ++ni)
          acc[mi][ni] = __builtin_amdgcn_mfma_f32_16x16x32_bf16(af[mi], bf_[ni], acc[mi][ni], 0, 0, 0);
      __builtin_amdgcn_s_setprio(0);
    }
    VMCNT0();                          // t+1's loads landed (hidden under MFMA)
    SBAR();                            // all reads of cur done; writes visible
    cur ^= 1;
  }

  // epilogue: C/D frag col = lane&15, row = (lane>>4)*4 + reg
#pragma unroll
  for (int mi = 0; mi < 8; ++mi) {
    const int row = bm + wm + mi * 16 + lg * 4;
#pragma unroll
    for (int ni = 0; ni < 4; ++ni) {
      const int col = bn + wn + ni * 16 + lq;
      const float* bp = bias.p[col >> 10];
      const float bvv = bp ? bp[col & (DD - 1)] : 0.f;
#pragma unroll
      for (int r = 0; r < 4; ++r) {
        float val = acc[mi][ni][r] + bvv;
        if (ACC)  val += C[(size_t)(row + r) * ldc + col];
        if (RELU) val = fmaxf(val, 0.f);
        if (OBF16) Cb[(size_t)(row + r) * ldc + col] = f2bf(val);
        else       C [(size_t)(row + r) * ldc + col] = val;
      }
    }
  }
}

// ---------------- gemm8: 256x128 tile, 8 waves, BK=64, 3-buffer counted pipeline ----
// Single barrier per K-tile: {issue 6 loads for t+2 -> 16 ds_read frags ->
// 32 MFMA -> vmcnt(6) -> s_barrier}. Used for N==1024 shapes.
template <int RELU, int ACC, int OBF16>
__global__ __launch_bounds__(512) void gemm8_mfma(const ushort* __restrict__ A,
                                                  const ushort* __restrict__ BT,
                                                  BiasP bias,
                                                  float* __restrict__ C,
                                                  ushort* __restrict__ Cb,
                                                  int M, int N, int K, int ldc) {
  __shared__ short8v As[3 * 2048];   // 96 KB
  __shared__ short8v Bs[3 * 1024];   // 48 KB
  const int tid  = threadIdx.x;
  const int w    = tid >> 6;
  const int lane = tid & 63;
  const int bm = blockIdx.y * 256;
  const int bn = blockIdx.x * 128;
  const int wm = (w >> 1) * 64;
  const int wn = (w & 1) * 64;
  const int lq = lane & 15;
  const int lg = lane >> 4;

  const ushort* aS[4];
  const ushort* bS[2];
#pragma unroll
  for (int i = 0; i < 4; ++i) {
    const int s   = w * 64 + i * 512 + lane;
    const int row = s >> 3;
    const int kg  = (s & 7) ^ (row & 7);
    aS[i] = A + (size_t)(bm + row) * K + kg * 8;
  }
#pragma unroll
  for (int i = 0; i < 2; ++i) {
    const int s   = w * 64 + i * 512 + lane;
    const int row = s >> 3;
    const int kg  = (s & 7) ^ (row & 7);
    bS[i] = BT + (size_t)(bn + row) * K + kg * 8;
  }

  int aIdx[4], bIdx[4];
#pragma unroll
  for (int i = 0; i < 4; ++i) {
    const int mr = wm + i * 16 + lq;
    aIdx[i] = mr * 8 + (lg ^ (mr & 7));
    const int nr = wn + i * 16 + lq;
    bIdx[i] = nr * 8 + (lg ^ (nr & 7));
  }

  floatx4 acc[4][4];
  const floatx4 fz = {0.f, 0.f, 0.f, 0.f};
#pragma unroll
  for (int mi = 0; mi < 4; ++mi)
#pragma unroll
    for (int ni = 0; ni < 4; ++ni) acc[mi][ni] = fz;

  const int nt = K >> 6;

  // prologue: stage tiles 0 and 1; wait tile 0 (6 of 12 remain outstanding)
#pragma unroll
  for (int b = 0; b < 2; ++b) {
    const int koff = b * 64;
    gll16(aS[0] + koff, &As[b * 2048 + w * 64 + 0 * 512]);
    gll16(aS[1] + koff, &As[b * 2048 + w * 64 + 1 * 512]);
    gll16(aS[2] + koff, &As[b * 2048 + w * 64 + 2 * 512]);
    gll16(aS[3] + koff, &As[b * 2048 + w * 64 + 3 * 512]);
    gll16(bS[0] + koff, &Bs[b * 1024 + w * 64 + 0 * 512]);
    gll16(bS[1] + koff, &Bs[b * 1024 + w * 64 + 1 * 512]);
  }
  VMCNT6();
  SBAR();

  int cur = 0;
  for (int t = 0; t < nt; ++t) {
    int b2 = cur + 2; if (b2 >= 3) b2 -= 3;
    const bool pf = (t + 2) < nt;
    if (pf) {
      const int ko = (t + 2) * 64;
      short8v* dA = &As[b2 * 2048 + w * 64];
      short8v* dB = &Bs[b2 * 1024 + w * 64];
      gll16(aS[0] + ko, dA + 0 * 512);
      gll16(aS[1] + ko, dA + 1 * 512);
      gll16(aS[2] + ko, dA + 2 * 512);
      gll16(aS[3] + ko, dA + 3 * 512);
      gll16(bS[0] + ko, dB + 0 * 512);
      gll16(bS[1] + ko, dB + 1 * 512);
    }
    const int cbA = cur * 2048, cbB = cur * 1024;
#pragma unroll
    for (int kk = 0; kk < 2; ++kk) {
      short8v af[4], bf_[4];
#pragma unroll
      for (int i = 0; i < 4; ++i) {
        af[i]  = As[cbA + (aIdx[i] ^ (kk * 4))];
        bf_[i] = Bs[cbB + (bIdx[i] ^ (kk * 4))];
      }
      __builtin_amdgcn_s_setprio(1);
#pragma unroll
      for (int mi = 0; mi < 4; ++mi)
#pragma unroll
        for (int ni = 0; ni < 4; ++ni)
          acc[mi][ni] = __builtin_amdgcn_mfma_f32_16x16x32_bf16(af[mi], bf_[ni], acc[mi][ni], 0, 0, 0);
      __builtin_amdgcn_s_setprio(0);
    }
    if (pf) { VMCNT6(); } else { VMCNT0(); }
    SBAR();
    cur = cur + 1; if (cur >= 3) cur -= 3;
  }

#pragma unroll
  for (int mi = 0; mi < 4; ++mi) {
    const int row = bm + wm + mi * 16 + lg * 4;
#pragma unroll
    for (int ni = 0; ni < 4; ++ni) {
      const int col = bn + wn + ni * 16 + lq;
      const float* bp = bias.p[col >> 10];
      const float bvv = bp ? bp[col & (DD - 1)] : 0.f;
#pragma unroll
      for (int r = 0; r < 4; ++r) {
        float val = acc[mi][ni][r] + bvv;
        if (ACC)  val += C[(size_t)(row + r) * ldc + col];
        if (RELU) val = fmaxf(val, 0.f);
        if (OBF16) Cb[(size_t)(row + r) * ldc + col] = f2bf(val);
        else       C [(size_t)(row + r) * ldc + col] = val;
      }
    }
  }
}

// modes: 1 = f32 ACC (+bias), 2 = bf16 + relu, 3 = bf16
static inline void launch_g(const ushort* A, const ushort* BT, BiasP bias,
                            float* C, ushort* Cb, int M, int N, int K, int ldc,
                            int mode, hipStream_t s) {
  if (N >= 2048) {
    dim3 grid(N / 256, M / 256), blk(512);
    if (mode == 1)      gemm256_mfma<0, 1, 0><<<grid, blk, 0, s>>>(A, BT, bias, C, Cb, M, N, K, ldc);
    else if (mode == 2) gemm256_mfma<1, 0, 1><<<grid, blk, 0, s>>>(A, BT, bias, C, Cb, M, N, K, ldc);
    else                gemm256_mfma<0, 0, 1><<<grid, blk, 0, s>>>(A, BT, bias, C, Cb, M, N, K, ldc);
  } else {
    dim3 grid(N / 128, M / 256), blk(512);
    if (mode == 1)      gemm8_mfma<0, 1, 0><<<grid, blk, 0, s>>>(A, BT, bias, C, Cb, M, N, K, ldc);
    else if (mode == 2) gemm8_mfma<1, 0, 1><<<grid, blk, 0, s>>>(A, BT, bias, C, Cb, M, N, K, ldc);
    else                gemm8_mfma<0, 0, 1><<<grid, blk, 0, s>>>(A, BT, bias, C, Cb, M, N, K, ldc);
  }
}

// ---------------- MFMA flash attention: one block per (b,h), 4 waves ----------------
template <int CAUSAL>
__global__ __launch_bounds__(256, 2) void attn_mfma_kernel(const ushort* __restrict__ q, int qs,
                                                           const ushort* __restrict__ k, int ks,
                                                           const ushort* __restrict__ v, int vs,
                                                           const int* __restrict__ qids,
                                                           ushort* __restrict__ out) {
  __shared__ short8v Kl[208 * 8];
  __shared__ ushort  Vt[64 * 256];
  __shared__ short8v Pl[1024];
  __shared__ float   padf[224];

  const int bh   = blockIdx.x;
  const int h    = bh & (NH - 1);
  const int b    = bh >> 4;
  const int tid  = threadIdx.x;
  const int w    = tid >> 6;
  const int lane = tid & 63;
  const int lq   = lane & 15;
  const int lg   = lane >> 4;

  if (tid < 208) {
    const int kp = tid;
    if (kp < SKV) {
      const short8v* src = (const short8v*)(k + ((size_t)(b * SKV + kp)) * ks + h * HDm);
#pragma unroll
      for (int s = 0; s < 8; ++s) Kl[kp * 8 + (s ^ (kp & 7))] = src[s];
    } else {
      const short8v z = {0, 0, 0, 0, 0, 0, 0, 0};
#pragma unroll
      for (int s = 0; s < 8; ++s) Kl[kp * 8 + s] = z;
    }
  }
  if (tid < 224) {
    const int kp = tid;
    float pf = 1.f;
    if (kp < SKV) {
      pf = CAUSAL ? ((qids[b * SQl + kp] == 0) ? 1.f : 0.f) : 0.f;
      const short8v* src = (const short8v*)(v + ((size_t)(b * SKV + kp)) * vs + h * HDm);
      const int s3 = kp >> 3, k7 = kp & 7;
#pragma unroll
      for (int li = 0; li < 8; ++li) {
        const short8v vv = src[li];
#pragma unroll
        for (int e = 0; e < 8; ++e)
          Vt[(li * 8 + e) * 256 + ((s3 ^ e) * 8) + k7] = (ushort)vv[e];
      }
    } else {
      const int s3 = kp >> 3, k7 = kp & 7;
#pragma unroll
      for (int li = 0; li < 8; ++li)
#pragma unroll
        for (int e = 0; e < 8; ++e)
          Vt[(li * 8 + e) * 256 + ((s3 ^ e) * 8) + k7] = 0;
    }
    padf[kp] = pf;
  }
  __syncthreads();

  short8v qf[4][2];
#pragma unroll
  for (int i = 0; i < 4; ++i) {
    const int mt = i * 4 + w;
    if (mt > 12) continue;
    int qrow = mt * 16 + lq;
    if (qrow > SQl - 1) qrow = SQl - 1;
    const ushort* qp = q + ((size_t)(b * SQl + qrow)) * qs + h * HDm + lg * 8;
    qf[i][0] = *(const short8v*)qp;
    qf[i][1] = *(const short8v*)(qp + 32);
  }

  float rmax[4][4];
#pragma unroll
  for (int i = 0; i < 4; ++i)
#pragma unroll
    for (int r = 0; r < 4; ++r) rmax[i][r] = -3e38f;

  for (int kt = 0; kt < 13; ++kt) {
    const int kp = kt * 16 + lq;
    const short8v bk0 = Kl[kp * 8 + (lg ^ (kp & 7))];
    const short8v bk1 = Kl[kp * 8 + ((4 + lg) ^ (kp & 7))];
    const float pmask = padf[kp];
#pragma unroll
    for (int i = 0; i < 4; ++i) {
      const int mt = i * 4 + w;
      if (mt > 12) continue;
      floatx4 S = {0.f, 0.f, 0.f, 0.f};
      S = __builtin_amdgcn_mfma_f32_16x16x32_bf16(qf[i][0], bk0, S, 0, 0, 0);
      S = __builtin_amdgcn_mfma_f32_16x16x32_bf16(qf[i][1], bk1, S, 0, 0, 0);
#pragma unroll
      for (int r = 0; r < 4; ++r) {
        const int qrow = mt * 16 + lg * 4 + r;
        bool masked = (pmask != 0.f);
        if (CAUSAL) masked = masked || (kp > qrow);
        const float s = masked ? -3e38f : S[r] * 0.125f;
        rmax[i][r] = fmaxf(rmax[i][r], s);
      }
    }
  }
#pragma unroll
  for (int msk = 1; msk < 16; msk <<= 1)
#pragma unroll
    for (int i = 0; i < 4; ++i)
#pragma unroll
      for (int r = 0; r < 4; ++r)
        rmax[i][r] = fmaxf(rmax[i][r], __shfl_xor(rmax[i][r], msk, 64));

  float rsum[4][4];
  floatx4 Of[4][4];
  const floatx4 fz = {0.f, 0.f, 0.f, 0.f};
#pragma unroll
  for (int i = 0; i < 4; ++i)
#pragma unroll
    for (int r = 0; r < 4; ++r) { rsum[i][r] = 0.f; Of[i][r] = fz; }

  for (int kc = 0; kc < 7; ++kc) {
#pragma unroll
    for (int t = 0; t < 2; ++t) {
      const int kt = kc * 2 + t;
      const int kp = kt * 16 + lq;
      short8v bk0, bk1;
      float pmask = 1.f;
      if (kt < 13) {
        bk0 = Kl[kp * 8 + (lg ^ (kp & 7))];
        bk1 = Kl[kp * 8 + ((4 + lg) ^ (kp & 7))];
        pmask = padf[kp];
      }
#pragma unroll
      for (int i = 0; i < 4; ++i) {
        const int mt = i * 4 + w;
        if (mt > 12) continue;
        floatx4 S = {0.f, 0.f, 0.f, 0.f};
        if (kt < 13) {
          S = __builtin_amdgcn_mfma_f32_16x16x32_bf16(qf[i][0], bk0, S, 0, 0, 0);
          S = __builtin_amdgcn_mfma_f32_16x16x32_bf16(qf[i][1], bk1, S, 0, 0, 0);
        }
#pragma unroll
        for (int r = 0; r < 4; ++r) {
          const int qrow = mt * 16 + lg * 4 + r;
          bool masked = (kt >= 13) || (pmask != 0.f);
          if (CAUSAL) masked = masked || (kp > qrow);
          const float p = masked ? 0.f : __expf(S[r] * 0.125f - rmax[i][r]);
          rsum[i][r] += p;
          const int qrl  = lg * 4 + r;
          const int kpl  = t * 16 + lq;
          const int slot = (kpl >> 3) ^ ((qrl >> 2) & 3);
          ((ushort*)Pl)[(w * 4 + i) * 512 + qrl * 32 + slot * 8 + (kpl & 7)] = f2bf(p);
        }
      }
    }
    short8v vb[4];
#pragma unroll
    for (int dt = 0; dt < 4; ++dt) {
      const int d  = dt * 16 + lq;
      const int sk = kc * 4 + lg;
      vb[dt] = ((const short8v*)Vt)[d * 32 + (sk ^ (d & 7))];
    }
#pragma unroll
    for (int i = 0; i < 4; ++i) {
      const int mt = i * 4 + w;
      if (mt > 12) continue;
      const short8v pa = Pl[(w * 4 + i) * 64 + lq * 4 + (lg ^ ((lq >> 2) & 3))];
#pragma unroll
      for (int dt = 0; dt < 4; ++dt)
        Of[i][dt] = __builtin_amdgcn_mfma_f32_16x16x32_bf16(pa, vb[dt], Of[i][dt], 0, 0, 0);
    }
  }

#pragma unroll
  for (int msk = 1; msk < 16; msk <<= 1)
#pragma unroll
    for (int i = 0; i < 4; ++i)
#pragma unroll
      for (int r = 0; r < 4; ++r)
        rsum[i][r] += __shfl_xor(rsum[i][r], msk, 64);

#pragma unroll
  for (int i = 0; i < 4; ++i) {
    const int mt = i * 4 + w;
    if (mt > 12) continue;
#pragma unroll
    for (int r = 0; r < 4; ++r) {
      const int qrow = mt * 16 + lg * 4 + r;
      if (qrow >= SQl) continue;
      const float linv = 1.0f / rsum[i][r];
      ushort* op = out + ((size_t)(b * SQl + qrow)) * DD + h * HDm;
#pragma unroll
      for (int dt = 0; dt < 4; ++dt)
        op[dt * 16 + lq] = f2bf(Of[i][dt][r] * linv);
    }
  }
}

// ---------------- driver ----------------
extern "C" void kernel_launch(void* const* d_in, const int* in_sizes, int n_in,
                              void* d_out, int out_size, void* d_ws, size_t ws_size,
                              hipStream_t stream) {
  (void)in_sizes; (void)n_in; (void)out_size; (void)ws_size;

  const int*   qids  = (const int*)  d_in[0];
  const float* key   = (const float*)d_in[1];
  const float* value = (const float*)d_in[2];
  const float* emb   = (const float*)d_in[3];
  const float* ln1_g = (const float*)d_in[4];
  const float* ln2_g = (const float*)d_in[5];
  const float* ln3_g = (const float*)d_in[6];
  const float* ln1_b = (const float*)d_in[7];
  const float* ln2_b = (const float*)d_in[8];
  const float* ln3_b = (const float*)d_in[9];
  const float* Wq_s  = (const float*)d_in[10];
  const float* Wk_s  = (const float*)d_in[11];
  const float* Wv_s  = (const float*)d_in[12];
  const float* Wo_s  = (const float*)d_in[13];
  const float* Wq_c  = (const float*)d_in[14];
  const float* Wk_c  = (const float*)d_in[15];
  const float* Wv_c  = (const float*)d_in[16];
  const float* Wo_c  = (const float*)d_in[17];
  const float* bq_s  = (const float*)d_in[18];
  const float* bk_s  = (const float*)d_in[19];
  const float* bv_s  = (const float*)d_in[20];
  const float* bq_c  = (const float*)d_in[21];
  const float* bk_c  = (const float*)d_in[22];
  const float* bv_c  = (const float*)d_in[23];
  const float* W1    = (const float*)d_in[24];
  const float* bf1   = (const float*)d_in[25];
  const float* W2    = (const float*)d_in[26];
  const float* bf2   = (const float*)d_in[27];
  const float* lnf_g = (const float*)d_in[28];
  const float* lnf_b = (const float*)d_in[29];

  const size_t NTOK = (size_t)BB * SQl * DD;     // 6,553,600
  const size_t MEL  = (size_t)DD * DD;
  char* w = (char*)d_ws;
  float*  o    = (float*)w;  w += NTOK * 4;
  ushort* t0b  = (ushort*)w; w += NTOK * 2;
  ushort* qkv  = (ushort*)w; w += (size_t)BB * SQl * 3 * DD * 2;
  ushort* kc   = (ushort*)w; w += (size_t)BB * SQl * 6 * DD * 2;
  ushort* vc   = (ushort*)w; w += (size_t)BB * SQl * 6 * DD * 2;
  ushort* kb   = (ushort*)w; w += NTOK * 2;
  ushort* vb   = (ushort*)w; w += NTOK * 2;
  ushort* fbb  = (ushort*)w; w += (size_t)BB * SQl * FFD * 2;
  ushort* wt   = (ushort*)w; w += 48 * MEL * 2;
  ushort* wt1  = (ushort*)w; w += (size_t)NL * DD * FFD * 2;
  ushort* wt2  = (ushort*)w; w += (size_t)NL * FFD * DD * 2;

  const int M = BB * SQl;                        // 6400
  const BiasP nob = {{nullptr, nullptr, nullptr, nullptr, nullptr, nullptr}};

  embed_pe_kernel<<<(int)(NTOK / 256), 256, 0, stream>>>(qids, emb, o);
  cvt_bf16_kernel<<<(int)(NTOK / 8 + 255) / 256, 256, 0, stream>>>(key,   kb, (int)(NTOK / 8));
  cvt_bf16_kernel<<<(int)(NTOK / 8 + 255) / 256, 256, 0, stream>>>(value, vb, (int)(NTOK / 8));

  P8 p8 = {{Wq_s, Wk_s, Wv_s, Wo_s, Wq_c, Wk_c, Wv_c, Wo_c}};
  transpose48_kernel<<<dim3(32, 32, 48), 256, 0, stream>>>(p8, wt);
  transposeW_kernel<<<dim3(FFD / 32, DD / 32, NL), 256, 0, stream>>>(W1, wt1, DD, FFD);
  transposeW_kernel<<<dim3(DD / 32, FFD / 32, NL), 256, 0, stream>>>(W2, wt2, FFD, DD);

  ushort* wtQKV = wt;                 // [l][3M]
  ushort* wtOs  = wt + 18 * MEL;      // [l][1M]
  ushort* wtQc  = wt + 24 * MEL;
  ushort* wtKc  = wt + 30 * MEL;
  ushort* wtVc  = wt + 36 * MEL;
  ushort* wtOc  = wt + 42 * MEL;

  // cross-attention K/V for ALL layers (layer-invariant A): two N=6144 GEMMs
  {
    BiasP bk6, bv6;
#pragma unroll
    for (int l = 0; l < NL; ++l) { bk6.p[l] = bk_c + l * DD; bv6.p[l] = bv_c + l * DD; }
    launch_g(kb, wtKc, bk6, nullptr, kc, M, 6 * DD, DD, 6 * DD, 3, stream);
    launch_g(vb, wtVc, bv6, nullptr, vc, M, 6 * DD, DD, 6 * DD, 3, stream);
  }

  for (int l = 0; l < NL; ++l) {
    // ---- self-attention ----
    ln4_kernel<1><<<M / 4, 256, 0, stream>>>(o, ln1_g + l * DD, ln1_b + l * DD, nullptr, t0b);
    BiasP bqkv = {{bq_s + l * DD, bk_s + l * DD, bv_s + l * DD, nullptr, nullptr, nullptr}};
    launch_g(t0b, wtQKV + l * 3 * MEL, bqkv, nullptr, qkv, M, 3 * DD, DD, 3 * DD, 3, stream);
    attn_mfma_kernel<1><<<BB * NH, 256, 0, stream>>>(qkv, 3 * DD, qkv + DD, 3 * DD,
                                                     qkv + 2 * DD, 3 * DD, qids, t0b);
    launch_g(t0b, wtOs + l * MEL, nob, o, nullptr, M, DD, DD, DD, 1, stream);

    // ---- cross-attention ----
    ln4_kernel<1><<<M / 4, 256, 0, stream>>>(o, ln2_g + l * DD, ln2_b + l * DD, nullptr, t0b);
    BiasP bqc = {{bq_c + l * DD, nullptr, nullptr, nullptr, nullptr, nullptr}};
    launch_g(t0b, wtQc + l * MEL, bqc, nullptr, qkv, M, DD, DD, 3 * DD, 3, stream);
    attn_mfma_kernel<0><<<BB * NH, 256, 0, stream>>>(qkv, 3 * DD, kc + l * DD, 6 * DD,
                                                     vc + l * DD, 6 * DD, nullptr, t0b);
    launch_g(t0b, wtOc + l * MEL, nob, o, nullptr, M, DD, DD, DD, 1, stream);

    // ---- feed-forward ----
    ln4_kernel<1><<<M / 4, 256, 0, stream>>>(o, ln3_g + l * DD, ln3_b + l * DD, nullptr, t0b);
    BiasP bf1p = {{bf1 + l * FFD, bf1 + l * FFD + DD, nullptr, nullptr, nullptr, nullptr}};
    launch_g(t0b, wt1 + (size_t)l * DD * FFD, bf1p, nullptr, fbb, M, FFD, DD, FFD, 2, stream);
    BiasP bf2p = {{bf2 + l * DD, nullptr, nullptr, nullptr, nullptr, nullptr}};
    launch_g(fbb, wt2 + (size_t)l * FFD * DD, bf2p, o, nullptr, M, DD, FFD, DD, 1, stream);
  }

  ln4_kernel<0><<<M / 4, 256, 0, stream>>>(o, lnf_g, lnf_b, (float*)d_out, nullptr);
}

// Round 8
// 2615.268 us; speedup vs baseline: 1.1212x; 1.1212x over previous
//
#include <hip/hip_runtime.h>
#include <math.h>

#define BB  32
#define SQl 200
#define SKV 200
#define DD  1024
#define NH  16
#define HDm 64
#define NL  6
#define FFD 2048

typedef __attribute__((ext_vector_type(8))) short  short8v;
typedef __attribute__((ext_vector_type(4))) float  floatx4;

#define SBAR()   asm volatile("s_barrier" ::: "memory")
#define VMCNT6() asm volatile("s_waitcnt vmcnt(6)" ::: "memory")
#define VMCNT0() asm volatile("s_waitcnt vmcnt(0)" ::: "memory")

// float -> bf16 bits, round-to-nearest-even
__device__ __forceinline__ ushort f2bf(float x) {
  uint u = __builtin_bit_cast(uint, x);
  u = (u + 0x7FFFu + ((u >> 16) & 1u)) >> 16;
  return (ushort)u;
}

__device__ __forceinline__ void gll16(const void* g, void* l) {
  __builtin_amdgcn_global_load_lds((const __attribute__((address_space(1))) void*)g,
                                   (__attribute__((address_space(3))) void*)l,
                                   16, 0, 0);
}

// ---------------- embedding + sinusoidal positional encoding ----------------
__global__ __launch_bounds__(256) void embed_pe_kernel(const int* __restrict__ qids,
                                                       const float* __restrict__ emb,
                                                       float* __restrict__ x) {
  int idx = blockIdx.x * 256 + threadIdx.x;
  int d   = idx & (DD - 1);
  int row = idx >> 10;
  int s   = row % SQl;
  int tok = qids[row];
  float expo = (float)(d & ~1) * (1.0f / (float)DD);
  float dv   = powf(10000.0f, expo);
  float ang  = (float)s / dv;
  float pe   = (d & 1) ? cosf(ang) : sinf(ang);
  x[idx] = emb[(size_t)tok * DD + d] + pe;
}

// ---------------- f32 -> bf16 elementwise ----------------
__global__ __launch_bounds__(256) void cvt_bf16_kernel(const float* __restrict__ in,
                                                       ushort* __restrict__ out, int n8) {
  int idx = blockIdx.x * 256 + threadIdx.x;
  if (idx >= n8) return;
  const floatx4 va = ((const floatx4*)in)[idx * 2];
  const floatx4 vb = ((const floatx4*)in)[idx * 2 + 1];
  short8v o;
  o[0] = (short)f2bf(va.x); o[1] = (short)f2bf(va.y);
  o[2] = (short)f2bf(va.z); o[3] = (short)f2bf(va.w);
  o[4] = (short)f2bf(vb.x); o[5] = (short)f2bf(vb.y);
  o[6] = (short)f2bf(vb.z); o[7] = (short)f2bf(vb.w);
  ((short8v*)out)[idx] = o;
}

// ---------------- batched transposes: W[K][N] f32 -> WT[N][K] bf16 ----------------
struct P8 { const float* p[8]; };
__global__ __launch_bounds__(256) void transpose48_kernel(P8 srcs, ushort* __restrict__ dst) {
  __shared__ float t[32][33];
  const size_t MEL = (size_t)DD * DD;
  const int z = blockIdx.z;
  const int arr = z / 6, l = z - arr * 6;
  const size_t base[8] = {0, MEL, 2*MEL, 18*MEL, 24*MEL, 30*MEL, 36*MEL, 42*MEL};
  const size_t lstr[8] = {3*MEL, 3*MEL, 3*MEL, MEL, MEL, MEL, MEL, MEL};
  const float* __restrict__ W = srcs.p[arr] + (size_t)l * MEL;
  ushort* __restrict__ WT = dst + base[arr] + (size_t)l * lstr[arr];
  const int n0 = blockIdx.x * 32, k0 = blockIdx.y * 32;
  const int tx = threadIdx.x & 31, ty = threadIdx.x >> 5;
#pragma unroll
  for (int i = 0; i < 4; ++i)
    t[ty + i * 8][tx] = W[(size_t)(k0 + ty + i * 8) * DD + n0 + tx];
  __syncthreads();
#pragma unroll
  for (int i = 0; i < 4; ++i)
    WT[(size_t)(n0 + ty + i * 8) * DD + k0 + tx] = f2bf(t[tx][ty + i * 8]);
}

__global__ __launch_bounds__(256) void transposeW_kernel(const float* __restrict__ src,
                                                         ushort* __restrict__ dst,
                                                         int K, int N) {
  __shared__ float t[32][33];
  const int z = blockIdx.z;
  const float* __restrict__ W = src + (size_t)z * K * N;
  ushort* __restrict__ WT = dst + (size_t)z * K * N;
  const int n0 = blockIdx.x * 32, k0 = blockIdx.y * 32;
  const int tx = threadIdx.x & 31, ty = threadIdx.x >> 5;
#pragma unroll
  for (int i = 0; i < 4; ++i)
    t[ty + i * 8][tx] = W[(size_t)(k0 + ty + i * 8) * N + n0 + tx];
  __syncthreads();
#pragma unroll
  for (int i = 0; i < 4; ++i)
    WT[(size_t)(n0 + ty + i * 8) * K + k0 + tx] = f2bf(t[tx][ty + i * 8]);
}

// ---------------- LayerNorm: wave per row, shfl-only reduction ----------------
template <int OBF16>
__global__ __launch_bounds__(256) void ln4_kernel(const float* __restrict__ in,
                                                  const float* __restrict__ gam,
                                                  const float* __restrict__ bet,
                                                  float* __restrict__ outf,
                                                  ushort* __restrict__ outb) {
  const int wid  = threadIdx.x >> 6;
  const int lane = threadIdx.x & 63;
  const int row  = blockIdx.x * 4 + wid;
  const float* ip = in + (size_t)row * DD;

  float4 x[4];
  float s = 0.f, sq = 0.f;
#pragma unroll
  for (int i = 0; i < 4; ++i) {
    x[i] = *(const float4*)&ip[i * 256 + lane * 4];
    s  += x[i].x + x[i].y + x[i].z + x[i].w;
    sq += x[i].x * x[i].x + x[i].y * x[i].y + x[i].z * x[i].z + x[i].w * x[i].w;
  }
#pragma unroll
  for (int msk = 1; msk < 64; msk <<= 1) {
    s  += __shfl_xor(s,  msk, 64);
    sq += __shfl_xor(sq, msk, 64);
  }
  const float m   = s * (1.0f / (float)DD);
  const float var = sq * (1.0f / (float)DD) - m * m;
  const float inv = rsqrtf(var + 1e-9f);

#pragma unroll
  for (int i = 0; i < 4; ++i) {
    const int c = i * 256 + lane * 4;
    const float4 g4 = *(const float4*)&gam[c];
    const float4 b4 = *(const float4*)&bet[c];
    float o0 = (x[i].x - m) * inv * g4.x + b4.x;
    float o1 = (x[i].y - m) * inv * g4.y + b4.y;
    float o2 = (x[i].z - m) * inv * g4.z + b4.z;
    float o3 = (x[i].w - m) * inv * g4.w + b4.w;
    if (OBF16) {
      uint2 pk;
      pk.x = (uint)f2bf(o0) | ((uint)f2bf(o1) << 16);
      pk.y = (uint)f2bf(o2) | ((uint)f2bf(o3) << 16);
      *(uint2*)&outb[(size_t)row * DD + c] = pk;
    } else {
      float4 ov; ov.x = o0; ov.y = o1; ov.z = o2; ov.w = o3;
      *(float4*)&outf[(size_t)row * DD + c] = ov;
    }
  }
}

struct BiasP { const float* p[6]; };   // bias.p[col>>10][col&1023]

// ---------------- gemm128: 128x128 tile, 4 waves, BK=64, single-buffer ----------
// Round-5 proven structure (best at N=6144), K-loop fully unrolled via NT so
// global_load_lds offsets fold to immediates and ds_read indices are static.
template <int RELU, int ACC, int OBF16, int NT>
__global__ __launch_bounds__(256) void gemm128_mfma(const ushort* __restrict__ A,
                                                    const ushort* __restrict__ BT,
                                                    BiasP bias,
                                                    float* __restrict__ C,
                                                    ushort* __restrict__ Cb,
                                                    int ldc) {
  constexpr int K = NT * 64;
  __shared__ short8v As[1024];   // 16 KB : [128 rows][8 slots]
  __shared__ short8v Bs[1024];   // 16 KB
  const int tid  = threadIdx.x;
  const int wid  = tid >> 6;
  const int lane = tid & 63;
  const int bm = blockIdx.y * 128;
  const int bn = blockIdx.x * 128;
  const int wm = (wid >> 1) * 64;
  const int wn = (wid & 1) * 64;
  const int lq = lane & 15;
  const int lg = lane >> 4;

  const ushort* aS[4];
  const ushort* bS[4];
#pragma unroll
  for (int i = 0; i < 4; ++i) {
    const int s   = i * 256 + wid * 64 + lane;
    const int row = s >> 3;
    const int kg  = (s & 7) ^ (row & 7);
    aS[i] = A  + (size_t)(bm + row) * K + kg * 8;
    bS[i] = BT + (size_t)(bn + row) * K + kg * 8;
  }

  int aIdx[4], bIdx[4];
#pragma unroll
  for (int i = 0; i < 4; ++i) {
    const int mr = wm + i * 16 + lq;
    aIdx[i] = mr * 8 + (lg ^ (mr & 7));
    const int nr = wn + i * 16 + lq;
    bIdx[i] = nr * 8 + (lg ^ (nr & 7));
  }

  floatx4 acc[4][4];
  const floatx4 fz = {0.f, 0.f, 0.f, 0.f};
#pragma unroll
  for (int mi = 0; mi < 4; ++mi)
#pragma unroll
    for (int ni = 0; ni < 4; ++ni) acc[mi][ni] = fz;

#pragma unroll
  for (int t = 0; t < NT; ++t) {
    const int ko = t * 64;
#pragma unroll
    for (int i = 0; i < 4; ++i) gll16(aS[i] + ko, &As[i * 256 + wid * 64]);
#pragma unroll
    for (int i = 0; i < 4; ++i) gll16(bS[i] + ko, &Bs[i * 256 + wid * 64]);
    __syncthreads();                       // drains vmcnt; LDS ready
#pragma unroll
    for (int kk = 0; kk < 2; ++kk) {
      short8v af[4], bf_[4];
#pragma unroll
      for (int i = 0; i < 4; ++i) {
        af[i]  = As[aIdx[i] ^ (kk * 4)];
        bf_[i] = Bs[bIdx[i] ^ (kk * 4)];
      }
#pragma unroll
      for (int mi = 0; mi < 4; ++mi)
#pragma unroll
        for (int ni = 0; ni < 4; ++ni)
          acc[mi][ni] = __builtin_amdgcn_mfma_f32_16x16x32_bf16(af[mi], bf_[ni], acc[mi][ni], 0, 0, 0);
    }
    __syncthreads();                       // reads done before next overwrite
  }

#pragma unroll
  for (int mi = 0; mi < 4; ++mi) {
    const int row = bm + wm + mi * 16 + lg * 4;
#pragma unroll
    for (int ni = 0; ni < 4; ++ni) {
      const int col = bn + wn + ni * 16 + lq;
      const float* bp = bias.p[col >> 10];
      const float bvv = bp ? bp[col & (DD - 1)] : 0.f;
#pragma unroll
      for (int r = 0; r < 4; ++r) {
        float val = acc[mi][ni][r] + bvv;
        if (ACC)  val += C[(size_t)(row + r) * ldc + col];
        if (RELU) val = fmaxf(val, 0.f);
        if (OBF16) Cb[(size_t)(row + r) * ldc + col] = f2bf(val);
        else       C [(size_t)(row + r) * ldc + col] = val;
      }
    }
  }
}

// ---------------- gemm8: 256x128 tile, 8 waves, BK=64, 3-buffer vmcnt(6) ----------
// Round-6 proven structure, K-loop fully unrolled via NT.
template <int RELU, int ACC, int OBF16, int NT>
__global__ __launch_bounds__(512) void gemm8_mfma(const ushort* __restrict__ A,
                                                  const ushort* __restrict__ BT,
                                                  BiasP bias,
                                                  float* __restrict__ C,
                                                  ushort* __restrict__ Cb,
                                                  int ldc) {
  constexpr int K = NT * 64;
  __shared__ short8v As[3 * 2048];   // 96 KB
  __shared__ short8v Bs[3 * 1024];   // 48 KB
  const int tid  = threadIdx.x;
  const int w    = tid >> 6;
  const int lane = tid & 63;
  const int bm = blockIdx.y * 256;
  const int bn = blockIdx.x * 128;
  const int wm = (w >> 1) * 64;
  const int wn = (w & 1) * 64;
  const int lq = lane & 15;
  const int lg = lane >> 4;

  const ushort* aS[4];
  const ushort* bS[2];
#pragma unroll
  for (int i = 0; i < 4; ++i) {
    const int s   = w * 64 + i * 512 + lane;
    const int row = s >> 3;
    const int kg  = (s & 7) ^ (row & 7);
    aS[i] = A + (size_t)(bm + row) * K + kg * 8;
  }
#pragma unroll
  for (int i = 0; i < 2; ++i) {
    const int s   = w * 64 + i * 512 + lane;
    const int row = s >> 3;
    const int kg  = (s & 7) ^ (row & 7);
    bS[i] = BT + (size_t)(bn + row) * K + kg * 8;
  }

  int aIdx[4], bIdx[4];
#pragma unroll
  for (int i = 0; i < 4; ++i) {
    const int mr = wm + i * 16 + lq;
    aIdx[i] = mr * 8 + (lg ^ (mr & 7));
    const int nr = wn + i * 16 + lq;
    bIdx[i] = nr * 8 + (lg ^ (nr & 7));
  }

  floatx4 acc[4][4];
  const floatx4 fz = {0.f, 0.f, 0.f, 0.f};
#pragma unroll
  for (int mi = 0; mi < 4; ++mi)
#pragma unroll
    for (int ni = 0; ni < 4; ++ni) acc[mi][ni] = fz;

  // prologue: stage tiles 0 and 1; wait tile 0 (6 of 12 remain outstanding)
#pragma unroll
  for (int b = 0; b < 2; ++b) {
    const int koff = b * 64;
    gll16(aS[0] + koff, &As[b * 2048 + w * 64 + 0 * 512]);
    gll16(aS[1] + koff, &As[b * 2048 + w * 64 + 1 * 512]);
    gll16(aS[2] + koff, &As[b * 2048 + w * 64 + 2 * 512]);
    gll16(aS[3] + koff, &As[b * 2048 + w * 64 + 3 * 512]);
    gll16(bS[0] + koff, &Bs[b * 1024 + w * 64 + 0 * 512]);
    gll16(bS[1] + koff, &Bs[b * 1024 + w * 64 + 1 * 512]);
  }
  VMCNT6();
  SBAR();

#pragma unroll
  for (int t = 0; t < NT; ++t) {
    const int cur = t % 3;
    const int b2  = (t + 2) % 3;
    const int ko2 = (t + 2) * 64;
    const bool pf = (t + 2) < NT;
    const int cbA = cur * 2048, cbB = cur * 1024;
    short8v* dA = &As[b2 * 2048 + w * 64];
    short8v* dB = &Bs[b2 * 1024 + w * 64];

    // ---- phase 1: ksub0 ----
    short8v af[4], bf_[4];
#pragma unroll
    for (int i = 0; i < 4; ++i) { af[i] = As[cbA + aIdx[i]]; bf_[i] = Bs[cbB + bIdx[i]]; }
    if (pf) {
      gll16(aS[0] + ko2, dA + 0 * 512);
      gll16(aS[1] + ko2, dA + 1 * 512);
      gll16(bS[0] + ko2, dB + 0 * 512);
    }
    SBAR();
    __builtin_amdgcn_s_setprio(1);
#pragma unroll
    for (int mi = 0; mi < 4; ++mi)
#pragma unroll
      for (int ni = 0; ni < 4; ++ni)
        acc[mi][ni] = __builtin_amdgcn_mfma_f32_16x16x32_bf16(af[mi], bf_[ni], acc[mi][ni], 0, 0, 0);
    __builtin_amdgcn_s_setprio(0);
    SBAR();

    // ---- phase 2: ksub1 ----
#pragma unroll
    for (int i = 0; i < 4; ++i) { af[i] = As[cbA + (aIdx[i] ^ 4)]; bf_[i] = Bs[cbB + (bIdx[i] ^ 4)]; }
    if (pf) {
      gll16(aS[2] + ko2, dA + 2 * 512);
      gll16(aS[3] + ko2, dA + 3 * 512);
      gll16(bS[1] + ko2, dB + 1 * 512);
    }
    SBAR();
    __builtin_amdgcn_s_setprio(1);
#pragma unroll
    for (int mi = 0; mi < 4; ++mi)
#pragma unroll
      for (int ni = 0; ni < 4; ++ni)
        acc[mi][ni] = __builtin_amdgcn_mfma_f32_16x16x32_bf16(af[mi], bf_[ni], acc[mi][ni], 0, 0, 0);
    __builtin_amdgcn_s_setprio(0);

    if (pf) { VMCNT6(); } else { VMCNT0(); }
    SBAR();
  }

#pragma unroll
  for (int mi = 0; mi < 4; ++mi) {
    const int row = bm + wm + mi * 16 + lg * 4;
#pragma unroll
    for (int ni = 0; ni < 4; ++ni) {
      const int col = bn + wn + ni * 16 + lq;
      const float* bp = bias.p[col >> 10];
      const float bvv = bp ? bp[col & (DD - 1)] : 0.f;
#pragma unroll
      for (int r = 0; r < 4; ++r) {
        float val = acc[mi][ni][r] + bvv;
        if (ACC)  val += C[(size_t)(row + r) * ldc + col];
        if (RELU) val = fmaxf(val, 0.f);
        if (OBF16) Cb[(size_t)(row + r) * ldc + col] = f2bf(val);
        else       C [(size_t)(row + r) * ldc + col] = val;
      }
    }
  }
}

// modes: 1 = f32 ACC (+bias), 2 = bf16 + relu, 3 = bf16
static inline void launch_g(const ushort* A, const ushort* BT, BiasP bias,
                            float* C, ushort* Cb, int M, int N, int K, int ldc,
                            int mode, hipStream_t s) {
  if (N == 6144) {                       // big cross-KV GEMMs: 128^2 4-wave kernel
    dim3 grid(N / 128, M / 128), blk(256);
    gemm128_mfma<0, 0, 1, 16><<<grid, blk, 0, s>>>(A, BT, bias, C, Cb, ldc);
    return;
  }
  dim3 grid(N / 128, M / 256), blk(512);
  if (K == 2048) {
    gemm8_mfma<0, 1, 0, 32><<<grid, blk, 0, s>>>(A, BT, bias, C, Cb, ldc);      // FF2
  } else if (mode == 1) {
    gemm8_mfma<0, 1, 0, 16><<<grid, blk, 0, s>>>(A, BT, bias, C, Cb, ldc);
  } else if (mode == 2) {
    gemm8_mfma<1, 0, 1, 16><<<grid, blk, 0, s>>>(A, BT, bias, C, Cb, ldc);
  } else {
    gemm8_mfma<0, 0, 1, 16><<<grid, blk, 0, s>>>(A, BT, bias, C, Cb, ldc);
  }
}

// ---------------- MFMA flash attention: one block per (b,h), 4 waves ----------------
template <int CAUSAL>
__global__ __launch_bounds__(256, 2) void attn_mfma_kernel(const ushort* __restrict__ q, int qs,
                                                           const ushort* __restrict__ k, int ks,
                                                           const ushort* __restrict__ v, int vs,
                                                           const int* __restrict__ qids,
                                                           ushort* __restrict__ out) {
  __shared__ short8v Kl[208 * 8];
  __shared__ ushort  Vt[64 * 256];
  __shared__ short8v Pl[1024];
  __shared__ float   padf[224];

  const int bh   = blockIdx.x;
  const int h    = bh & (NH - 1);
  const int b    = bh >> 4;
  const int tid  = threadIdx.x;
  const int w    = tid >> 6;
  const int lane = tid & 63;
  const int lq   = lane & 15;
  const int lg   = lane >> 4;

  if (tid < 208) {
    const int kp = tid;
    if (kp < SKV) {
      const short8v* src = (const short8v*)(k + ((size_t)(b * SKV + kp)) * ks + h * HDm);
#pragma unroll
      for (int s = 0; s < 8; ++s) Kl[kp * 8 + (s ^ (kp & 7))] = src[s];
    } else {
      const short8v z = {0, 0, 0, 0, 0, 0, 0, 0};
#pragma unroll
      for (int s = 0; s < 8; ++s) Kl[kp * 8 + s] = z;
    }
  }
  if (tid < 224) {
    const int kp = tid;
    float pf = 1.f;
    if (kp < SKV) {
      pf = CAUSAL ? ((qids[b * SQl + kp] == 0) ? 1.f : 0.f) : 0.f;
      const short8v* src = (const short8v*)(v + ((size_t)(b * SKV + kp)) * vs + h * HDm);
      const int s3 = kp >> 3, k7 = kp & 7;
#pragma unroll
      for (int li = 0; li < 8; ++li) {
        const short8v vv = src[li];
#pragma unroll
        for (int e = 0; e < 8; ++e)
          Vt[(li * 8 + e) * 256 + ((s3 ^ e) * 8) + k7] = (ushort)vv[e];
      }
    } else {
      const int s3 = kp >> 3, k7 = kp & 7;
#pragma unroll
      for (int li = 0; li < 8; ++li)
#pragma unroll
        for (int e = 0; e < 8; ++e)
          Vt[(li * 8 + e) * 256 + ((s3 ^ e) * 8) + k7] = 0;
    }
    padf[kp] = pf;
  }
  __syncthreads();

  short8v qf[4][2];
#pragma unroll
  for (int i = 0; i < 4; ++i) {
    const int mt = i * 4 + w;
    if (mt > 12) continue;
    int qrow = mt * 16 + lq;
    if (qrow > SQl - 1) qrow = SQl - 1;
    const ushort* qp = q + ((size_t)(b * SQl + qrow)) * qs + h * HDm + lg * 8;
    qf[i][0] = *(const short8v*)qp;
    qf[i][1] = *(const short8v*)(qp + 32);
  }

  float rmax[4][4];
#pragma unroll
  for (int i = 0; i < 4; ++i)
#pragma unroll
    for (int r = 0; r < 4; ++r) rmax[i][r] = -3e38f;

  for (int kt = 0; kt < 13; ++kt) {
    const int kp = kt * 16 + lq;
    const short8v bk0 = Kl[kp * 8 + (lg ^ (kp & 7))];
    const short8v bk1 = Kl[kp * 8 + ((4 + lg) ^ (kp & 7))];
    const float pmask = padf[kp];
#pragma unroll
    for (int i = 0; i < 4; ++i) {
      const int mt = i * 4 + w;
      if (mt > 12) continue;
      floatx4 S = {0.f, 0.f, 0.f, 0.f};
      S = __builtin_amdgcn_mfma_f32_16x16x32_bf16(qf[i][0], bk0, S, 0, 0, 0);
      S = __builtin_amdgcn_mfma_f32_16x16x32_bf16(qf[i][1], bk1, S, 0, 0, 0);
#pragma unroll
      for (int r = 0; r < 4; ++r) {
        const int qrow = mt * 16 + lg * 4 + r;
        bool masked = (pmask != 0.f);
        if (CAUSAL) masked = masked || (kp > qrow);
        const float s = masked ? -3e38f : S[r] * 0.125f;
        rmax[i][r] = fmaxf(rmax[i][r], s);
      }
    }
  }
#pragma unroll
  for (int msk = 1; msk < 16; msk <<= 1)
#pragma unroll
    for (int i = 0; i < 4; ++i)
#pragma unroll
      for (int r = 0; r < 4; ++r)
        rmax[i][r] = fmaxf(rmax[i][r], __shfl_xor(rmax[i][r], msk, 64));

  float rsum[4][4];
  floatx4 Of[4][4];
  const floatx4 fz = {0.f, 0.f, 0.f, 0.f};
#pragma unroll
  for (int i = 0; i < 4; ++i)
#pragma unroll
    for (int r = 0; r < 4; ++r) { rsum[i][r] = 0.f; Of[i][r] = fz; }

  for (int kc = 0; kc < 7; ++kc) {
#pragma unroll
    for (int t = 0; t < 2; ++t) {
      const int kt = kc * 2 + t;
      const int kp = kt * 16 + lq;
      short8v bk0, bk1;
      float pmask = 1.f;
      if (kt < 13) {
        bk0 = Kl[kp * 8 + (lg ^ (kp & 7))];
        bk1 = Kl[kp * 8 + ((4 + lg) ^ (kp & 7))];
        pmask = padf[kp];
      }
#pragma unroll
      for (int i = 0; i < 4; ++i) {
        const int mt = i * 4 + w;
        if (mt > 12) continue;
        floatx4 S = {0.f, 0.f, 0.f, 0.f};
        if (kt < 13) {
          S = __builtin_amdgcn_mfma_f32_16x16x32_bf16(qf[i][0], bk0, S, 0, 0, 0);
          S = __builtin_amdgcn_mfma_f32_16x16x32_bf16(qf[i][1], bk1, S, 0, 0, 0);
        }
#pragma unroll
        for (int r = 0; r < 4; ++r) {
          const int qrow = mt * 16 + lg * 4 + r;
          bool masked = (kt >= 13) || (pmask != 0.f);
          if (CAUSAL) masked = masked || (kp > qrow);
          const float p = masked ? 0.f : __expf(S[r] * 0.125f - rmax[i][r]);
          rsum[i][r] += p;
          const int qrl  = lg * 4 + r;
          const int kpl  = t * 16 + lq;
          const int slot = (kpl >> 3) ^ ((qrl >> 2) & 3);
          ((ushort*)Pl)[(w * 4 + i) * 512 + qrl * 32 + slot * 8 + (kpl & 7)] = f2bf(p);
        }
      }
    }
    short8v vb[4];
#pragma unroll
    for (int dt = 0; dt < 4; ++dt) {
      const int d  = dt * 16 + lq;
      const int sk = kc * 4 + lg;
      vb[dt] = ((const short8v*)Vt)[d * 32 + (sk ^ (d & 7))];
    }
#pragma unroll
    for (int i = 0; i < 4; ++i) {
      const int mt = i * 4 + w;
      if (mt > 12) continue;
      const short8v pa = Pl[(w * 4 + i) * 64 + lq * 4 + (lg ^ ((lq >> 2) & 3))];
#pragma unroll
      for (int dt = 0; dt < 4; ++dt)
        Of[i][dt] = __builtin_amdgcn_mfma_f32_16x16x32_bf16(pa, vb[dt], Of[i][dt], 0, 0, 0);
    }
  }

#pragma unroll
  for (int msk = 1; msk < 16; msk <<= 1)
#pragma unroll
    for (int i = 0; i < 4; ++i)
#pragma unroll
      for (int r = 0; r < 4; ++r)
        rsum[i][r] += __shfl_xor(rsum[i][r], msk, 64);

#pragma unroll
  for (int i = 0; i < 4; ++i) {
    const int mt = i * 4 + w;
    if (mt > 12) continue;
#pragma unroll
    for (int r = 0; r < 4; ++r) {
      const int qrow = mt * 16 + lg * 4 + r;
      if (qrow >= SQl) continue;
      const float linv = 1.0f / rsum[i][r];
      ushort* op = out + ((size_t)(b * SQl + qrow)) * DD + h * HDm;
#pragma unroll
      for (int dt = 0; dt < 4; ++dt)
        op[dt * 16 + lq] = f2bf(Of[i][dt][r] * linv);
    }
  }
}

// ---------------- driver ----------------
extern "C" void kernel_launch(void* const* d_in, const int* in_sizes, int n_in,
                              void* d_out, int out_size, void* d_ws, size_t ws_size,
                              hipStream_t stream) {
  (void)in_sizes; (void)n_in; (void)out_size; (void)ws_size;

  const int*   qids  = (const int*)  d_in[0];
  const float* key   = (const float*)d_in[1];
  const float* value = (const float*)d_in[2];
  const float* emb   = (const float*)d_in[3];
  const float* ln1_g = (const float*)d_in[4];
  const float* ln2_g = (const float*)d_in[5];
  const float* ln3_g = (const float*)d_in[6];
  const float* ln1_b = (const float*)d_in[7];
  const float* ln2_b = (const float*)d_in[8];
  const float* ln3_b = (const float*)d_in[9];
  const float* Wq_s  = (const float*)d_in[10];
  const float* Wk_s  = (const float*)d_in[11];
  const float* Wv_s  = (const float*)d_in[12];
  const float* Wo_s  = (const float*)d_in[13];
  const float* Wq_c  = (const float*)d_in[14];
  const float* Wk_c  = (const float*)d_in[15];
  const float* Wv_c  = (const float*)d_in[16];
  const float* Wo_c  = (const float*)d_in[17];
  const float* bq_s  = (const float*)d_in[18];
  const float* bk_s  = (const float*)d_in[19];
  const float* bv_s  = (const float*)d_in[20];
  const float* bq_c  = (const float*)d_in[21];
  const float* bk_c  = (const float*)d_in[22];
  const float* bv_c  = (const float*)d_in[23];
  const float* W1    = (const float*)d_in[24];
  const float* bf1   = (const float*)d_in[25];
  const float* W2    = (const float*)d_in[26];
  const float* bf2   = (const float*)d_in[27];
  const float* lnf_g = (const float*)d_in[28];
  const float* lnf_b = (const float*)d_in[29];

  const size_t NTOK = (size_t)BB * SQl * DD;     // 6,553,600
  const size_t MEL  = (size_t)DD * DD;
  char* w = (char*)d_ws;
  float*  o    = (float*)w;  w += NTOK * 4;
  ushort* t0b  = (ushort*)w; w += NTOK * 2;
  ushort* qkv  = (ushort*)w; w += (size_t)BB * SQl * 3 * DD * 2;
  ushort* kc   = (ushort*)w; w += (size_t)BB * SQl * 6 * DD * 2;
  ushort* vc   = (ushort*)w; w += (size_t)BB * SQl * 6 * DD * 2;
  ushort* kb   = (ushort*)w; w += NTOK * 2;
  ushort* vb   = (ushort*)w; w += NTOK * 2;
  ushort* fbb  = (ushort*)w; w += (size_t)BB * SQl * FFD * 2;
  ushort* wt   = (ushort*)w; w += 48 * MEL * 2;
  ushort* wt1  = (ushort*)w; w += (size_t)NL * DD * FFD * 2;
  ushort* wt2  = (ushort*)w; w += (size_t)NL * FFD * DD * 2;

  const int M = BB * SQl;                        // 6400
  const BiasP nob = {{nullptr, nullptr, nullptr, nullptr, nullptr, nullptr}};

  embed_pe_kernel<<<(int)(NTOK / 256), 256, 0, stream>>>(qids, emb, o);
  cvt_bf16_kernel<<<(int)(NTOK / 8 + 255) / 256, 256, 0, stream>>>(key,   kb, (int)(NTOK / 8));
  cvt_bf16_kernel<<<(int)(NTOK / 8 + 255) / 256, 256, 0, stream>>>(value, vb, (int)(NTOK / 8));

  P8 p8 = {{Wq_s, Wk_s, Wv_s, Wo_s, Wq_c, Wk_c, Wv_c, Wo_c}};
  transpose48_kernel<<<dim3(32, 32, 48), 256, 0, stream>>>(p8, wt);
  transposeW_kernel<<<dim3(FFD / 32, DD / 32, NL), 256, 0, stream>>>(W1, wt1, DD, FFD);
  transposeW_kernel<<<dim3(DD / 32, FFD / 32, NL), 256, 0, stream>>>(W2, wt2, FFD, DD);

  ushort* wtQKV = wt;                 // [l][3M]
  ushort* wtOs  = wt + 18 * MEL;      // [l][1M]
  ushort* wtQc  = wt + 24 * MEL;
  ushort* wtKc  = wt + 30 * MEL;
  ushort* wtVc  = wt + 36 * MEL;
  ushort* wtOc  = wt + 42 * MEL;

  // cross-attention K/V for ALL layers (layer-invariant A): two N=6144 GEMMs
  {
    BiasP bk6, bv6;
#pragma unroll
    for (int l = 0; l < NL; ++l) { bk6.p[l] = bk_c + l * DD; bv6.p[l] = bv_c + l * DD; }
    launch_g(kb, wtKc, bk6, nullptr, kc, M, 6 * DD, DD, 6 * DD, 3, stream);
    launch_g(vb, wtVc, bv6, nullptr, vc, M, 6 * DD, DD, 6 * DD, 3, stream);
  }

  for (int l = 0; l < NL; ++l) {
    // ---- self-attention ----
    ln4_kernel<1><<<M / 4, 256, 0, stream>>>(o, ln1_g + l * DD, ln1_b + l * DD, nullptr, t0b);
    BiasP bqkv = {{bq_s + l * DD, bk_s + l * DD, bv_s + l * DD, nullptr, nullptr, nullptr}};
    launch_g(t0b, wtQKV + l * 3 * MEL, bqkv, nullptr, qkv, M, 3 * DD, DD, 3 * DD, 3, stream);
    attn_mfma_kernel<1><<<BB * NH, 256, 0, stream>>>(qkv, 3 * DD, qkv + DD, 3 * DD,
                                                     qkv + 2 * DD, 3 * DD, qids, t0b);
    launch_g(t0b, wtOs + l * MEL, nob, o, nullptr, M, DD, DD, DD, 1, stream);

    // ---- cross-attention ----
    ln4_kernel<1><<<M / 4, 256, 0, stream>>>(o, ln2_g + l * DD, ln2_b + l * DD, nullptr, t0b);
    BiasP bqc = {{bq_c + l * DD, nullptr, nullptr, nullptr, nullptr, nullptr}};
    launch_g(t0b, wtQc + l * MEL, bqc, nullptr, qkv, M, DD, DD, 3 * DD, 3, stream);
    attn_mfma_kernel<0><<<BB * NH, 256, 0, stream>>>(qkv, 3 * DD, kc + l * DD, 6 * DD,
                                                     vc + l * DD, 6 * DD, nullptr, t0b);
    launch_g(t0b, wtOc + l * MEL, nob, o, nullptr, M, DD, DD, DD, 1, stream);

    // ---- feed-forward ----
    ln4_kernel<1><<<M / 4, 256, 0, stream>>>(o, ln3_g + l * DD, ln3_b + l * DD, nullptr, t0b);
    BiasP bf1p = {{bf1 + l * FFD, bf1 + l * FFD + DD, nullptr, nullptr, nullptr, nullptr}};
    launch_g(t0b, wt1 + (size_t)l * DD * FFD, bf1p, nullptr, fbb, M, FFD, DD, FFD, 2, stream);
    BiasP bf2p = {{bf2 + l * DD, nullptr, nullptr, nullptr, nullptr, nullptr}};
    launch_g(fbb, wt2 + (size_t)l * FFD * DD, bf2p, o, nullptr, M, DD, FFD, DD, 1, stream);
  }

  ln4_kernel<0><<<M / 4, 256, 0, stream>>>(o, lnf_g, lnf_b, (float*)d_out, nullptr);
}

// Round 9
// 2382.211 us; speedup vs baseline: 1.2309x; 1.0978x over previous
//
#include <hip/hip_runtime.h>
#include <math.h>

#define BB  32
#define SQl 200
#define SKV 200
#define DD  1024
#define NH  16
#define HDm 64
#define NL  6
#define FFD 2048

typedef __attribute__((ext_vector_type(8))) short  short8v;
typedef __attribute__((ext_vector_type(4))) float  floatx4;

// float -> bf16 bits, round-to-nearest-even
__device__ __forceinline__ ushort f2bf(float x) {
  uint u = __builtin_bit_cast(uint, x);
  u = (u + 0x7FFFu + ((u >> 16) & 1u)) >> 16;
  return (ushort)u;
}

__device__ __forceinline__ void gll16(const void* g, void* l) {
  __builtin_amdgcn_global_load_lds((const __attribute__((address_space(1))) void*)g,
                                   (__attribute__((address_space(3))) void*)l,
                                   16, 0, 0);
}

// ---------------- embedding + sinusoidal positional encoding ----------------
__global__ __launch_bounds__(256) void embed_pe_kernel(const int* __restrict__ qids,
                                                       const float* __restrict__ emb,
                                                       float* __restrict__ x) {
  int idx = blockIdx.x * 256 + threadIdx.x;
  int d   = idx & (DD - 1);
  int row = idx >> 10;
  int s   = row % SQl;
  int tok = qids[row];
  float expo = (float)(d & ~1) * (1.0f / (float)DD);
  float dv   = powf(10000.0f, expo);
  float ang  = (float)s / dv;
  float pe   = (d & 1) ? cosf(ang) : sinf(ang);
  x[idx] = emb[(size_t)tok * DD + d] + pe;
}

// ---------------- f32 -> bf16 elementwise ----------------
__global__ __launch_bounds__(256) void cvt_bf16_kernel(const float* __restrict__ in,
                                                       ushort* __restrict__ out, int n8) {
  int idx = blockIdx.x * 256 + threadIdx.x;
  if (idx >= n8) return;
  const floatx4 va = ((const floatx4*)in)[idx * 2];
  const floatx4 vb = ((const floatx4*)in)[idx * 2 + 1];
  short8v o;
  o[0] = (short)f2bf(va.x); o[1] = (short)f2bf(va.y);
  o[2] = (short)f2bf(va.z); o[3] = (short)f2bf(va.w);
  o[4] = (short)f2bf(vb.x); o[5] = (short)f2bf(vb.y);
  o[6] = (short)f2bf(vb.z); o[7] = (short)f2bf(vb.w);
  ((short8v*)out)[idx] = o;
}

// ---------------- batched transposes: W[K][N] f32 -> WT[N][K] bf16 ----------------
struct P8 { const float* p[8]; };
__global__ __launch_bounds__(256) void transpose48_kernel(P8 srcs, ushort* __restrict__ dst) {
  __shared__ float t[32][33];
  const size_t MEL = (size_t)DD * DD;
  const int z = blockIdx.z;
  const int arr = z / 6, l = z - arr * 6;
  const size_t base[8] = {0, MEL, 2*MEL, 18*MEL, 24*MEL, 30*MEL, 36*MEL, 42*MEL};
  const size_t lstr[8] = {3*MEL, 3*MEL, 3*MEL, MEL, MEL, MEL, MEL, MEL};
  const float* __restrict__ W = srcs.p[arr] + (size_t)l * MEL;
  ushort* __restrict__ WT = dst + base[arr] + (size_t)l * lstr[arr];
  const int n0 = blockIdx.x * 32, k0 = blockIdx.y * 32;
  const int tx = threadIdx.x & 31, ty = threadIdx.x >> 5;
#pragma unroll
  for (int i = 0; i < 4; ++i)
    t[ty + i * 8][tx] = W[(size_t)(k0 + ty + i * 8) * DD + n0 + tx];
  __syncthreads();
#pragma unroll
  for (int i = 0; i < 4; ++i)
    WT[(size_t)(n0 + ty + i * 8) * DD + k0 + tx] = f2bf(t[tx][ty + i * 8]);
}

__global__ __launch_bounds__(256) void transposeW_kernel(const float* __restrict__ src,
                                                         ushort* __restrict__ dst,
                                                         int K, int N) {
  __shared__ float t[32][33];
  const int z = blockIdx.z;
  const float* __restrict__ W = src + (size_t)z * K * N;
  ushort* __restrict__ WT = dst + (size_t)z * K * N;
  const int n0 = blockIdx.x * 32, k0 = blockIdx.y * 32;
  const int tx = threadIdx.x & 31, ty = threadIdx.x >> 5;
#pragma unroll
  for (int i = 0; i < 4; ++i)
    t[ty + i * 8][tx] = W[(size_t)(k0 + ty + i * 8) * N + n0 + tx];
  __syncthreads();
#pragma unroll
  for (int i = 0; i < 4; ++i)
    WT[(size_t)(n0 + ty + i * 8) * K + k0 + tx] = f2bf(t[tx][ty + i * 8]);
}

// ---------------- LayerNorm: wave per row, shfl-only reduction ----------------
template <int OBF16>
__global__ __launch_bounds__(256) void ln4_kernel(const float* __restrict__ in,
                                                  const float* __restrict__ gam,
                                                  const float* __restrict__ bet,
                                                  float* __restrict__ outf,
                                                  ushort* __restrict__ outb) {
  const int wid  = threadIdx.x >> 6;
  const int lane = threadIdx.x & 63;
  const int row  = blockIdx.x * 4 + wid;
  const float* ip = in + (size_t)row * DD;

  float4 x[4];
  float s = 0.f, sq = 0.f;
#pragma unroll
  for (int i = 0; i < 4; ++i) {
    x[i] = *(const float4*)&ip[i * 256 + lane * 4];
    s  += x[i].x + x[i].y + x[i].z + x[i].w;
    sq += x[i].x * x[i].x + x[i].y * x[i].y + x[i].z * x[i].z + x[i].w * x[i].w;
  }
#pragma unroll
  for (int msk = 1; msk < 64; msk <<= 1) {
    s  += __shfl_xor(s,  msk, 64);
    sq += __shfl_xor(sq, msk, 64);
  }
  const float m   = s * (1.0f / (float)DD);
  const float var = sq * (1.0f / (float)DD) - m * m;
  const float inv = rsqrtf(var + 1e-9f);

#pragma unroll
  for (int i = 0; i < 4; ++i) {
    const int c = i * 256 + lane * 4;
    const float4 g4 = *(const float4*)&gam[c];
    const float4 b4 = *(const float4*)&bet[c];
    float o0 = (x[i].x - m) * inv * g4.x + b4.x;
    float o1 = (x[i].y - m) * inv * g4.y + b4.y;
    float o2 = (x[i].z - m) * inv * g4.z + b4.z;
    float o3 = (x[i].w - m) * inv * g4.w + b4.w;
    if (OBF16) {
      uint2 pk;
      pk.x = (uint)f2bf(o0) | ((uint)f2bf(o1) << 16);
      pk.y = (uint)f2bf(o2) | ((uint)f2bf(o3) << 16);
      *(uint2*)&outb[(size_t)row * DD + c] = pk;
    } else {
      float4 ov; ov.x = o0; ov.y = o1; ov.z = o2; ov.w = o3;
      *(float4*)&outf[(size_t)row * DD + c] = ov;
    }
  }
}

struct BiasP { const float* p[6]; };   // bias.p[col>>10][col&1023]

// ---------------- gemm128: 128x128 tile, 4 waves, BK=64, single-buffer ----------
// Best-measured structure (r8: 29.5% MfmaUtil, beats all deep-pipelined variants).
// 32 KB LDS -> up to 5 blocks/CU; cross-block wave overlap hides the per-tile
// vmcnt(0) drain. K-loop fully unrolled (NT) so global_load_lds offsets fold to
// immediates and ds_read indices are static. XCD-aware bijective block swizzle
// (T1; all grids here have nwg % 8 == 0).
template <int RELU, int ACC, int OBF16, int NT>
__global__ __launch_bounds__(256) void gemm128_mfma(const ushort* __restrict__ A,
                                                    const ushort* __restrict__ BT,
                                                    BiasP bias,
                                                    float* __restrict__ C,
                                                    ushort* __restrict__ Cb,
                                                    int ldc) {
  constexpr int K = NT * 64;
  __shared__ short8v As[1024];   // 16 KB : [128 rows][8 slots]
  __shared__ short8v Bs[1024];   // 16 KB
  const int tid  = threadIdx.x;
  const int wid  = tid >> 6;
  const int lane = tid & 63;

  // XCD swizzle: contiguous chunk of tiles per XCD (bijective: nwg % 8 == 0)
  const int nwg = gridDim.x * gridDim.y;
  int wg = blockIdx.y * gridDim.x + blockIdx.x;
  wg = (wg & 7) * (nwg >> 3) + (wg >> 3);
  const int bn = (wg % gridDim.x) * 128;
  const int bm = (wg / gridDim.x) * 128;

  const int wm = (wid >> 1) * 64;
  const int wn = (wid & 1) * 64;
  const int lq = lane & 15;
  const int lg = lane >> 4;

  const ushort* aS[4];
  const ushort* bS[4];
#pragma unroll
  for (int i = 0; i < 4; ++i) {
    const int s   = i * 256 + wid * 64 + lane;
    const int row = s >> 3;
    const int kg  = (s & 7) ^ (row & 7);
    aS[i] = A  + (size_t)(bm + row) * K + kg * 8;
    bS[i] = BT + (size_t)(bn + row) * K + kg * 8;
  }

  int aIdx[4], bIdx[4];
#pragma unroll
  for (int i = 0; i < 4; ++i) {
    const int mr = wm + i * 16 + lq;
    aIdx[i] = mr * 8 + (lg ^ (mr & 7));
    const int nr = wn + i * 16 + lq;
    bIdx[i] = nr * 8 + (lg ^ (nr & 7));
  }

  floatx4 acc[4][4];
  const floatx4 fz = {0.f, 0.f, 0.f, 0.f};
#pragma unroll
  for (int mi = 0; mi < 4; ++mi)
#pragma unroll
    for (int ni = 0; ni < 4; ++ni) acc[mi][ni] = fz;

#pragma unroll
  for (int t = 0; t < NT; ++t) {
    const int ko = t * 64;
#pragma unroll
    for (int i = 0; i < 4; ++i) gll16(aS[i] + ko, &As[i * 256 + wid * 64]);
#pragma unroll
    for (int i = 0; i < 4; ++i) gll16(bS[i] + ko, &Bs[i * 256 + wid * 64]);
    __syncthreads();                       // drains vmcnt; LDS ready
#pragma unroll
    for (int kk = 0; kk < 2; ++kk) {
      short8v af[4], bf_[4];
#pragma unroll
      for (int i = 0; i < 4; ++i) {
        af[i]  = As[aIdx[i] ^ (kk * 4)];
        bf_[i] = Bs[bIdx[i] ^ (kk * 4)];
      }
#pragma unroll
      for (int mi = 0; mi < 4; ++mi)
#pragma unroll
        for (int ni = 0; ni < 4; ++ni)
          acc[mi][ni] = __builtin_amdgcn_mfma_f32_16x16x32_bf16(af[mi], bf_[ni], acc[mi][ni], 0, 0, 0);
    }
    __syncthreads();                       // reads done before next overwrite
  }

#pragma unroll
  for (int mi = 0; mi < 4; ++mi) {
    const int row = bm + wm + mi * 16 + lg * 4;
#pragma unroll
    for (int ni = 0; ni < 4; ++ni) {
      const int col = bn + wn + ni * 16 + lq;
      const float* bp = bias.p[col >> 10];
      const float bvv = bp ? bp[col & (DD - 1)] : 0.f;
#pragma unroll
      for (int r = 0; r < 4; ++r) {
        float val = acc[mi][ni][r] + bvv;
        if (ACC)  val += C[(size_t)(row + r) * ldc + col];
        if (RELU) val = fmaxf(val, 0.f);
        if (OBF16) Cb[(size_t)(row + r) * ldc + col] = f2bf(val);
        else       C [(size_t)(row + r) * ldc + col] = val;
      }
    }
  }
}

// modes: 1 = f32 ACC (+bias), 2 = bf16 + relu, 3 = bf16
static inline void launch_g(const ushort* A, const ushort* BT, BiasP bias,
                            float* C, ushort* Cb, int M, int N, int K, int ldc,
                            int mode, hipStream_t s) {
  dim3 grid(N / 128, M / 128), blk(256);
  if (K == 2048) {       // FF2 (always mode 1)
    gemm128_mfma<0, 1, 0, 32><<<grid, blk, 0, s>>>(A, BT, bias, C, Cb, ldc);
  } else if (mode == 1) {
    gemm128_mfma<0, 1, 0, 16><<<grid, blk, 0, s>>>(A, BT, bias, C, Cb, ldc);
  } else if (mode == 2) {
    gemm128_mfma<1, 0, 1, 16><<<grid, blk, 0, s>>>(A, BT, bias, C, Cb, ldc);
  } else {
    gemm128_mfma<0, 0, 1, 16><<<grid, blk, 0, s>>>(A, BT, bias, C, Cb, ldc);
  }
}

// ---------------- MFMA flash attention: one block per (b,h), 4 waves ----------------
template <int CAUSAL>
__global__ __launch_bounds__(256, 2) void attn_mfma_kernel(const ushort* __restrict__ q, int qs,
                                                           const ushort* __restrict__ k, int ks,
                                                           const ushort* __restrict__ v, int vs,
                                                           const int* __restrict__ qids,
                                                           ushort* __restrict__ out) {
  __shared__ short8v Kl[208 * 8];
  __shared__ ushort  Vt[64 * 256];
  __shared__ short8v Pl[1024];
  __shared__ float   padf[224];

  const int bh   = blockIdx.x;
  const int h    = bh & (NH - 1);
  const int b    = bh >> 4;
  const int tid  = threadIdx.x;
  const int w    = tid >> 6;
  const int lane = tid & 63;
  const int lq   = lane & 15;
  const int lg   = lane >> 4;

  if (tid < 208) {
    const int kp = tid;
    if (kp < SKV) {
      const short8v* src = (const short8v*)(k + ((size_t)(b * SKV + kp)) * ks + h * HDm);
#pragma unroll
      for (int s = 0; s < 8; ++s) Kl[kp * 8 + (s ^ (kp & 7))] = src[s];
    } else {
      const short8v z = {0, 0, 0, 0, 0, 0, 0, 0};
#pragma unroll
      for (int s = 0; s < 8; ++s) Kl[kp * 8 + s] = z;
    }
  }
  if (tid < 224) {
    const int kp = tid;
    float pf = 1.f;
    if (kp < SKV) {
      pf = CAUSAL ? ((qids[b * SQl + kp] == 0) ? 1.f : 0.f) : 0.f;
      const short8v* src = (const short8v*)(v + ((size_t)(b * SKV + kp)) * vs + h * HDm);
      const int s3 = kp >> 3, k7 = kp & 7;
#pragma unroll
      for (int li = 0; li < 8; ++li) {
        const short8v vv = src[li];
#pragma unroll
        for (int e = 0; e < 8; ++e)
          Vt[(li * 8 + e) * 256 + ((s3 ^ e) * 8) + k7] = (ushort)vv[e];
      }
    } else {
      const int s3 = kp >> 3, k7 = kp & 7;
#pragma unroll
      for (int li = 0; li < 8; ++li)
#pragma unroll
        for (int e = 0; e < 8; ++e)
          Vt[(li * 8 + e) * 256 + ((s3 ^ e) * 8) + k7] = 0;
    }
    padf[kp] = pf;
  }
  __syncthreads();

  short8v qf[4][2];
#pragma unroll
  for (int i = 0; i < 4; ++i) {
    const int mt = i * 4 + w;
    if (mt > 12) continue;
    int qrow = mt * 16 + lq;
    if (qrow > SQl - 1) qrow = SQl - 1;
    const ushort* qp = q + ((size_t)(b * SQl + qrow)) * qs + h * HDm + lg * 8;
    qf[i][0] = *(const short8v*)qp;
    qf[i][1] = *(const short8v*)(qp + 32);
  }

  float rmax[4][4];
#pragma unroll
  for (int i = 0; i < 4; ++i)
#pragma unroll
    for (int r = 0; r < 4; ++r) rmax[i][r] = -3e38f;

  for (int kt = 0; kt < 13; ++kt) {
    const int kp = kt * 16 + lq;
    const short8v bk0 = Kl[kp * 8 + (lg ^ (kp & 7))];
    const short8v bk1 = Kl[kp * 8 + ((4 + lg) ^ (kp & 7))];
    const float pmask = padf[kp];
#pragma unroll
    for (int i = 0; i < 4; ++i) {
      const int mt = i * 4 + w;
      if (mt > 12) continue;
      floatx4 S = {0.f, 0.f, 0.f, 0.f};
      S = __builtin_amdgcn_mfma_f32_16x16x32_bf16(qf[i][0], bk0, S, 0, 0, 0);
      S = __builtin_amdgcn_mfma_f32_16x16x32_bf16(qf[i][1], bk1, S, 0, 0, 0);
#pragma unroll
      for (int r = 0; r < 4; ++r) {
        const int qrow = mt * 16 + lg * 4 + r;
        bool masked = (pmask != 0.f);
        if (CAUSAL) masked = masked || (kp > qrow);
        const float s = masked ? -3e38f : S[r] * 0.125f;
        rmax[i][r] = fmaxf(rmax[i][r], s);
      }
    }
  }
#pragma unroll
  for (int msk = 1; msk < 16; msk <<= 1)
#pragma unroll
    for (int i = 0; i < 4; ++i)
#pragma unroll
      for (int r = 0; r < 4; ++r)
        rmax[i][r] = fmaxf(rmax[i][r], __shfl_xor(rmax[i][r], msk, 64));

  float rsum[4][4];
  floatx4 Of[4][4];
  const floatx4 fz = {0.f, 0.f, 0.f, 0.f};
#pragma unroll
  for (int i = 0; i < 4; ++i)
#pragma unroll
    for (int r = 0; r < 4; ++r) { rsum[i][r] = 0.f; Of[i][r] = fz; }

  for (int kc = 0; kc < 7; ++kc) {
#pragma unroll
    for (int t = 0; t < 2; ++t) {
      const int kt = kc * 2 + t;
      const int kp = kt * 16 + lq;
      short8v bk0, bk1;
      float pmask = 1.f;
      if (kt < 13) {
        bk0 = Kl[kp * 8 + (lg ^ (kp & 7))];
        bk1 = Kl[kp * 8 + ((4 + lg) ^ (kp & 7))];
        pmask = padf[kp];
      }
#pragma unroll
      for (int i = 0; i < 4; ++i) {
        const int mt = i * 4 + w;
        if (mt > 12) continue;
        floatx4 S = {0.f, 0.f, 0.f, 0.f};
        if (kt < 13) {
          S = __builtin_amdgcn_mfma_f32_16x16x32_bf16(qf[i][0], bk0, S, 0, 0, 0);
          S = __builtin_amdgcn_mfma_f32_16x16x32_bf16(qf[i][1], bk1, S, 0, 0, 0);
        }
#pragma unroll
        for (int r = 0; r < 4; ++r) {
          const int qrow = mt * 16 + lg * 4 + r;
          bool masked = (kt >= 13) || (pmask != 0.f);
          if (CAUSAL) masked = masked || (kp > qrow);
          const float p = masked ? 0.f : __expf(S[r] * 0.125f - rmax[i][r]);
          rsum[i][r] += p;
          const int qrl  = lg * 4 + r;
          const int kpl  = t * 16 + lq;
          const int slot = (kpl >> 3) ^ ((qrl >> 2) & 3);
          ((ushort*)Pl)[(w * 4 + i) * 512 + qrl * 32 + slot * 8 + (kpl & 7)] = f2bf(p);
        }
      }
    }
    short8v vb[4];
#pragma unroll
    for (int dt = 0; dt < 4; ++dt) {
      const int d  = dt * 16 + lq;
      const int sk = kc * 4 + lg;
      vb[dt] = ((const short8v*)Vt)[d * 32 + (sk ^ (d & 7))];
    }
#pragma unroll
    for (int i = 0; i < 4; ++i) {
      const int mt = i * 4 + w;
      if (mt > 12) continue;
      const short8v pa = Pl[(w * 4 + i) * 64 + lq * 4 + (lg ^ ((lq >> 2) & 3))];
#pragma unroll
      for (int dt = 0; dt < 4; ++dt)
        Of[i][dt] = __builtin_amdgcn_mfma_f32_16x16x32_bf16(pa, vb[dt], Of[i][dt], 0, 0, 0);
    }
  }

#pragma unroll
  for (int msk = 1; msk < 16; msk <<= 1)
#pragma unroll
    for (int i = 0; i < 4; ++i)
#pragma unroll
      for (int r = 0; r < 4; ++r)
        rsum[i][r] += __shfl_xor(rsum[i][r], msk, 64);

#pragma unroll
  for (int i = 0; i < 4; ++i) {
    const int mt = i * 4 + w;
    if (mt > 12) continue;
#pragma unroll
    for (int r = 0; r < 4; ++r) {
      const int qrow = mt * 16 + lg * 4 + r;
      if (qrow >= SQl) continue;
      const float linv = 1.0f / rsum[i][r];
      ushort* op = out + ((size_t)(b * SQl + qrow)) * DD + h * HDm;
#pragma unroll
      for (int dt = 0; dt < 4; ++dt)
        op[dt * 16 + lq] = f2bf(Of[i][dt][r] * linv);
    }
  }
}

// ---------------- driver ----------------
extern "C" void kernel_launch(void* const* d_in, const int* in_sizes, int n_in,
                              void* d_out, int out_size, void* d_ws, size_t ws_size,
                              hipStream_t stream) {
  (void)in_sizes; (void)n_in; (void)out_size; (void)ws_size;

  const int*   qids  = (const int*)  d_in[0];
  const float* key   = (const float*)d_in[1];
  const float* value = (const float*)d_in[2];
  const float* emb   = (const float*)d_in[3];
  const float* ln1_g = (const float*)d_in[4];
  const float* ln2_g = (const float*)d_in[5];
  const float* ln3_g = (const float*)d_in[6];
  const float* ln1_b = (const float*)d_in[7];
  const float* ln2_b = (const float*)d_in[8];
  const float* ln3_b = (const float*)d_in[9];
  const float* Wq_s  = (const float*)d_in[10];
  const float* Wk_s  = (const float*)d_in[11];
  const float* Wv_s  = (const float*)d_in[12];
  const float* Wo_s  = (const float*)d_in[13];
  const float* Wq_c  = (const float*)d_in[14];
  const float* Wk_c  = (const float*)d_in[15];
  const float* Wv_c  = (const float*)d_in[16];
  const float* Wo_c  = (const float*)d_in[17];
  const float* bq_s  = (const float*)d_in[18];
  const float* bk_s  = (const float*)d_in[19];
  const float* bv_s  = (const float*)d_in[20];
  const float* bq_c  = (const float*)d_in[21];
  const float* bk_c  = (const float*)d_in[22];
  const float* bv_c  = (const float*)d_in[23];
  const float* W1    = (const float*)d_in[24];
  const float* bf1   = (const float*)d_in[25];
  const float* W2    = (const float*)d_in[26];
  const float* bf2   = (const float*)d_in[27];
  const float* lnf_g = (const float*)d_in[28];
  const float* lnf_b = (const float*)d_in[29];

  const size_t NTOK = (size_t)BB * SQl * DD;     // 6,553,600
  const size_t MEL  = (size_t)DD * DD;
  char* w = (char*)d_ws;
  float*  o    = (float*)w;  w += NTOK * 4;
  ushort* t0b  = (ushort*)w; w += NTOK * 2;
  ushort* qkv  = (ushort*)w; w += (size_t)BB * SQl * 3 * DD * 2;
  ushort* kc   = (ushort*)w; w += (size_t)BB * SQl * 6 * DD * 2;
  ushort* vc   = (ushort*)w; w += (size_t)BB * SQl * 6 * DD * 2;
  ushort* kb   = (ushort*)w; w += NTOK * 2;
  ushort* vb   = (ushort*)w; w += NTOK * 2;
  ushort* fbb  = (ushort*)w; w += (size_t)BB * SQl * FFD * 2;
  ushort* wt   = (ushort*)w; w += 48 * MEL * 2;
  ushort* wt1  = (ushort*)w; w += (size_t)NL * DD * FFD * 2;
  ushort* wt2  = (ushort*)w; w += (size_t)NL * FFD * DD * 2;

  const int M = BB * SQl;                        // 6400
  const BiasP nob = {{nullptr, nullptr, nullptr, nullptr, nullptr, nullptr}};

  embed_pe_kernel<<<(int)(NTOK / 256), 256, 0, stream>>>(qids, emb, o);
  cvt_bf16_kernel<<<(int)(NTOK / 8 + 255) / 256, 256, 0, stream>>>(key,   kb, (int)(NTOK / 8));
  cvt_bf16_kernel<<<(int)(NTOK / 8 + 255) / 256, 256, 0, stream>>>(value, vb, (int)(NTOK / 8));

  P8 p8 = {{Wq_s, Wk_s, Wv_s, Wo_s, Wq_c, Wk_c, Wv_c, Wo_c}};
  transpose48_kernel<<<dim3(32, 32, 48), 256, 0, stream>>>(p8, wt);
  transposeW_kernel<<<dim3(FFD / 32, DD / 32, NL), 256, 0, stream>>>(W1, wt1, DD, FFD);
  transposeW_kernel<<<dim3(DD / 32, FFD / 32, NL), 256, 0, stream>>>(W2, wt2, FFD, DD);

  ushort* wtQKV = wt;                 // [l][3M]
  ushort* wtOs  = wt + 18 * MEL;      // [l][1M]
  ushort* wtQc  = wt + 24 * MEL;
  ushort* wtKc  = wt + 30 * MEL;
  ushort* wtVc  = wt + 36 * MEL;
  ushort* wtOc  = wt + 42 * MEL;

  // cross-attention K/V for ALL layers (layer-invariant A): two N=6144 GEMMs
  {
    BiasP bk6, bv6;
#pragma unroll
    for (int l = 0; l < NL; ++l) { bk6.p[l] = bk_c + l * DD; bv6.p[l] = bv_c + l * DD; }
    launch_g(kb, wtKc, bk6, nullptr, kc, M, 6 * DD, DD, 6 * DD, 3, stream);
    launch_g(vb, wtVc, bv6, nullptr, vc, M, 6 * DD, DD, 6 * DD, 3, stream);
  }

  for (int l = 0; l < NL; ++l) {
    // ---- self-attention ----
    ln4_kernel<1><<<M / 4, 256, 0, stream>>>(o, ln1_g + l * DD, ln1_b + l * DD, nullptr, t0b);
    BiasP bqkv = {{bq_s + l * DD, bk_s + l * DD, bv_s + l * DD, nullptr, nullptr, nullptr}};
    launch_g(t0b, wtQKV + l * 3 * MEL, bqkv, nullptr, qkv, M, 3 * DD, DD, 3 * DD, 3, stream);
    attn_mfma_kernel<1><<<BB * NH, 256, 0, stream>>>(qkv, 3 * DD, qkv + DD, 3 * DD,
                                                     qkv + 2 * DD, 3 * DD, qids, t0b);
    launch_g(t0b, wtOs + l * MEL, nob, o, nullptr, M, DD, DD, DD, 1, stream);

    // ---- cross-attention ----
    ln4_kernel<1><<<M / 4, 256, 0, stream>>>(o, ln2_g + l * DD, ln2_b + l * DD, nullptr, t0b);
    BiasP bqc = {{bq_c + l * DD, nullptr, nullptr, nullptr, nullptr, nullptr}};
    launch_g(t0b, wtQc + l * MEL, bqc, nullptr, qkv, M, DD, DD, 3 * DD, 3, stream);
    attn_mfma_kernel<0><<<BB * NH, 256, 0, stream>>>(qkv, 3 * DD, kc + l * DD, 6 * DD,
                                                     vc + l * DD, 6 * DD, nullptr, t0b);
    launch_g(t0b, wtOc + l * MEL, nob, o, nullptr, M, DD, DD, DD, 1, stream);

    // ---- feed-forward ----
    ln4_kernel<1><<<M / 4, 256, 0, stream>>>(o, ln3_g + l * DD, ln3_b + l * DD, nullptr, t0b);
    BiasP bf1p = {{bf1 + l * FFD, bf1 + l * FFD + DD, nullptr, nullptr, nullptr, nullptr}};
    launch_g(t0b, wt1 + (size_t)l * DD * FFD, bf1p, nullptr, fbb, M, FFD, DD, FFD, 2, stream);
    BiasP bf2p = {{bf2 + l * DD, nullptr, nullptr, nullptr, nullptr, nullptr}};
    launch_g(fbb, wt2 + (size_t)l * FFD * DD, bf2p, o, nullptr, M, DD, FFD, DD, 1, stream);
  }

  ln4_kernel<0><<<M / 4, 256, 0, stream>>>(o, lnf_g, lnf_b, (float*)d_out, nullptr);
}